// Round 1
// baseline (3600.807 us; speedup 1.0000x reference)
//
#include <hip/hip_runtime.h>

#define D 64
#define H 128

__device__ __forceinline__ float wave_sum(float v) {
#pragma unroll
  for (int off = 32; off > 0; off >>= 1) v += __shfl_xor(v, off, 64);
  return v;
}

// ---------------- Kernel 1: edge scatter (u_add_e + segment_sum + degree) ----
__global__ __launch_bounds__(256) void k_scatter(
    const float* __restrict__ node, const float* __restrict__ edge,
    const int* __restrict__ src, const int* __restrict__ dst,
    float* __restrict__ agg, float* __restrict__ deg, int E)
{
  int idx = blockIdx.x * 256 + threadIdx.x;
  int e = idx >> 4;           // 16 threads per edge, float4 each
  if (e >= E) return;
  int f = (idx & 15) << 2;
  int s = src[e];
  int d = dst[e];
  float4 ev = *(const float4*)(edge + (size_t)e * D + f);
  float4 nv = *(const float4*)(node + (size_t)s * D + f);
  float* ap = agg + (size_t)d * D + f;
  atomicAdd(ap + 0, ev.x + nv.x);
  atomicAdd(ap + 1, ev.y + nv.y);
  atomicAdd(ap + 2, ev.z + nv.z);
  atomicAdd(ap + 3, ev.w + nv.w);
  if ((idx & 15) == 0) atomicAdd(deg + d, 1.0f);
}

// ---------------- Kernel 2: combine + GEMM1 + BN1 stats ---------------------
__global__ __launch_bounds__(256) void k_gemm1(
    const float* __restrict__ node, const float* __restrict__ agg,
    const float* __restrict__ deg, const float* __restrict__ epsp,
    const float* __restrict__ W1, const float* __restrict__ b1,
    float* __restrict__ h1, float* __restrict__ sum1, float* __restrict__ sq1, int N)
{
  int row = blockIdx.x * 256 + threadIdx.x;
  bool active = row < N;
  float h[D];
  float e1 = 1.0f + epsp[0];
  if (active) {
    float rdeg = 1.0f / fmaxf(deg[row], 1.0f);
#pragma unroll
    for (int j = 0; j < D; j += 4) {
      float4 nv = *(const float4*)(node + (size_t)row * D + j);
      float4 av = *(const float4*)(agg + (size_t)row * D + j);
      h[j + 0] = fmaf(e1, nv.x, av.x * rdeg);
      h[j + 1] = fmaf(e1, nv.y, av.y * rdeg);
      h[j + 2] = fmaf(e1, nv.z, av.z * rdeg);
      h[j + 3] = fmaf(e1, nv.w, av.w * rdeg);
    }
  } else {
#pragma unroll
    for (int j = 0; j < D; ++j) h[j] = 0.0f;
  }

  for (int k = 0; k < H; k += 4) {
    float a0 = b1[k + 0], a1 = b1[k + 1], a2 = b1[k + 2], a3 = b1[k + 3];
#pragma unroll
    for (int j = 0; j < D; ++j) {
      float4 wv = *(const float4*)(W1 + (size_t)j * H + k);  // wave-uniform -> s_load
      a0 = fmaf(h[j], wv.x, a0);
      a1 = fmaf(h[j], wv.y, a1);
      a2 = fmaf(h[j], wv.z, a2);
      a3 = fmaf(h[j], wv.w, a3);
    }
    float v0 = active ? a0 : 0.0f;
    float v1 = active ? a1 : 0.0f;
    float v2 = active ? a2 : 0.0f;
    float v3 = active ? a3 : 0.0f;
    float s0 = wave_sum(v0), q0 = wave_sum(v0 * v0);
    float s1 = wave_sum(v1), q1 = wave_sum(v1 * v1);
    float s2 = wave_sum(v2), q2 = wave_sum(v2 * v2);
    float s3 = wave_sum(v3), q3 = wave_sum(v3 * v3);
    if ((threadIdx.x & 63) == 0) {
      atomicAdd(sum1 + k + 0, s0); atomicAdd(sq1 + k + 0, q0);
      atomicAdd(sum1 + k + 1, s1); atomicAdd(sq1 + k + 1, q1);
      atomicAdd(sum1 + k + 2, s2); atomicAdd(sq1 + k + 2, q2);
      atomicAdd(sum1 + k + 3, s3); atomicAdd(sq1 + k + 3, q3);
    }
    if (active) *(float4*)(h1 + (size_t)row * H + k) = make_float4(a0, a1, a2, a3);
  }
}

// ---------------- Kernel 3/5: BN scale/shift finalize -----------------------
__global__ void k_finalize(const float* __restrict__ sum, const float* __restrict__ sq,
                           const float* __restrict__ gamma, const float* __restrict__ beta,
                           float* __restrict__ scale, float* __restrict__ shift,
                           int C, float invN)
{
  int k = threadIdx.x;
  if (k < C) {
    float m = sum[k] * invN;
    float var = fmaf(-m, m, sq[k] * invN);
    float sc = gamma[k] * rsqrtf(var + 1e-5f);
    scale[k] = sc;
    shift[k] = fmaf(-m, sc, beta[k]);
  }
}

// ---------------- Kernel 4: BN1+ReLU + GEMM2 + BN2 stats --------------------
__global__ __launch_bounds__(256) void k_gemm2(
    const float* __restrict__ h1, const float* __restrict__ scale1,
    const float* __restrict__ shift1, const float* __restrict__ W2,
    const float* __restrict__ b2, float* __restrict__ out,
    float* __restrict__ sum2, float* __restrict__ sq2, int N)
{
  int row = blockIdx.x * 256 + threadIdx.x;
  bool active = row < N;
  float acc[D];
#pragma unroll
  for (int k = 0; k < D; ++k) acc[k] = 0.0f;

  if (active) {
    for (int j = 0; j < H; j += 4) {
      float4 hv = *(const float4*)(h1 + (size_t)row * H + j);
      float x0 = fmaxf(fmaf(hv.x, scale1[j + 0], shift1[j + 0]), 0.0f);
      float x1 = fmaxf(fmaf(hv.y, scale1[j + 1], shift1[j + 1]), 0.0f);
      float x2 = fmaxf(fmaf(hv.z, scale1[j + 2], shift1[j + 2]), 0.0f);
      float x3 = fmaxf(fmaf(hv.w, scale1[j + 3], shift1[j + 3]), 0.0f);
      const float* w0 = W2 + (size_t)(j + 0) * D;
      const float* w1 = W2 + (size_t)(j + 1) * D;
      const float* w2 = W2 + (size_t)(j + 2) * D;
      const float* w3 = W2 + (size_t)(j + 3) * D;
#pragma unroll
      for (int k = 0; k < D; ++k) {
        float a = acc[k];
        a = fmaf(x0, w0[k], a);   // wave-uniform W -> s_load + v_fmac(sgpr)
        a = fmaf(x1, w1[k], a);
        a = fmaf(x2, w2[k], a);
        a = fmaf(x3, w3[k], a);
        acc[k] = a;
      }
    }
  }

  for (int k = 0; k < D; k += 4) {
    float a0 = acc[k + 0] + b2[k + 0];
    float a1 = acc[k + 1] + b2[k + 1];
    float a2 = acc[k + 2] + b2[k + 2];
    float a3 = acc[k + 3] + b2[k + 3];
    float v0 = active ? a0 : 0.0f;
    float v1 = active ? a1 : 0.0f;
    float v2 = active ? a2 : 0.0f;
    float v3 = active ? a3 : 0.0f;
    float s0 = wave_sum(v0), q0 = wave_sum(v0 * v0);
    float s1 = wave_sum(v1), q1 = wave_sum(v1 * v1);
    float s2 = wave_sum(v2), q2 = wave_sum(v2 * v2);
    float s3 = wave_sum(v3), q3 = wave_sum(v3 * v3);
    if ((threadIdx.x & 63) == 0) {
      atomicAdd(sum2 + k + 0, s0); atomicAdd(sq2 + k + 0, q0);
      atomicAdd(sum2 + k + 1, s1); atomicAdd(sq2 + k + 1, q1);
      atomicAdd(sum2 + k + 2, s2); atomicAdd(sq2 + k + 2, q2);
      atomicAdd(sum2 + k + 3, s3); atomicAdd(sq2 + k + 3, q3);
    }
    if (active) *(float4*)(out + (size_t)row * D + k) = make_float4(a0, a1, a2, a3);
  }
}

// ---------------- Kernel 6: final BN2 + ReLU (in-place on d_out) ------------
__global__ __launch_bounds__(256) void k_bnrelu(
    float* __restrict__ out, const float* __restrict__ scale2,
    const float* __restrict__ shift2, size_t n4)
{
  size_t idx = (size_t)blockIdx.x * 256 + threadIdx.x;
  if (idx >= n4) return;
  int k = (int)((idx * 4) & (D - 1));
  float4 v = *(float4*)(out + idx * 4);
  v.x = fmaxf(fmaf(v.x, scale2[k + 0], shift2[k + 0]), 0.0f);
  v.y = fmaxf(fmaf(v.y, scale2[k + 1], shift2[k + 1]), 0.0f);
  v.z = fmaxf(fmaf(v.z, scale2[k + 2], shift2[k + 2]), 0.0f);
  v.w = fmaxf(fmaf(v.w, scale2[k + 3], shift2[k + 3]), 0.0f);
  *(float4*)(out + idx * 4) = v;
}

extern "C" void kernel_launch(void* const* d_in, const int* in_sizes, int n_in,
                              void* d_out, int out_size, void* d_ws, size_t ws_size,
                              hipStream_t stream)
{
  const float* node   = (const float*)d_in[0];
  const float* edge   = (const float*)d_in[1];
  const int*   src    = (const int*)d_in[2];
  const int*   dst    = (const int*)d_in[3];
  const float* eps    = (const float*)d_in[4];
  const float* W1     = (const float*)d_in[5];
  const float* b1     = (const float*)d_in[6];
  const float* gamma1 = (const float*)d_in[7];
  const float* beta1  = (const float*)d_in[8];
  const float* W2     = (const float*)d_in[9];
  const float* b2     = (const float*)d_in[10];
  const float* gamma2 = (const float*)d_in[11];
  const float* beta2  = (const float*)d_in[12];
  float* out = (float*)d_out;
  float* ws  = (float*)d_ws;

  const int N = in_sizes[0] / D;
  const int E = in_sizes[2];

  // workspace layout (floats)
  float* agg    = ws;                      // N*D
  float* deg    = agg + (size_t)N * D;     // N
  float* sum1   = deg + N;                 // H
  float* sq1    = sum1 + H;                // H
  float* sum2   = sq1 + H;                 // D
  float* sq2    = sum2 + D;                // D   -- end of zeroed region
  float* scale1 = sq2 + D;                 // H
  float* shift1 = scale1 + H;              // H
  float* scale2 = shift1 + H;              // D
  float* shift2 = scale2 + D;              // D
  float* h1     = shift2 + D;              // N*H (16B-aligned: N*65+768 floats)

  size_t zero_bytes = ((size_t)N * D + N + 2 * H + 2 * D) * sizeof(float);
  hipMemsetAsync(d_ws, 0, zero_bytes, stream);

  k_scatter<<<(E * 16 + 255) / 256, 256, 0, stream>>>(node, edge, src, dst, agg, deg, E);

  int nb = (N + 255) / 256;
  k_gemm1<<<nb, 256, 0, stream>>>(node, agg, deg, eps, W1, b1, h1, sum1, sq1, N);
  k_finalize<<<1, H, 0, stream>>>(sum1, sq1, gamma1, beta1, scale1, shift1, H, 1.0f / (float)N);
  k_gemm2<<<nb, 256, 0, stream>>>(h1, scale1, shift1, W2, b2, out, sum2, sq2, N);
  k_finalize<<<1, D, 0, stream>>>(sum2, sq2, gamma2, beta2, scale2, shift2, D, 1.0f / (float)N);

  size_t n4 = (size_t)N * D / 4;
  k_bnrelu<<<(int)((n4 + 255) / 256), 256, 0, stream>>>(out, scale2, shift2, n4);
}

// Round 2
// 2779.077 us; speedup vs baseline: 1.2957x; 1.2957x over previous
//
#include <hip/hip_runtime.h>

#define D 64
#define H 128

__device__ __forceinline__ float wave_sum(float v) {
#pragma unroll
  for (int off = 32; off > 0; off >>= 1) v += __shfl_xor(v, off, 64);
  return v;
}

// ---------------- CSR build ----------------
__global__ __launch_bounds__(256) void k_hist(const int* __restrict__ dst,
                                              int* __restrict__ cnt, int E) {
  int e = blockIdx.x * 256 + threadIdx.x;
  if (e < E) atomicAdd(cnt + dst[e], 1);
}

__global__ __launch_bounds__(256) void k_alloc(const int* __restrict__ cnt,
                                               int* __restrict__ offs,
                                               int* __restrict__ cursor,
                                               int* __restrict__ total, int N) {
  int n = blockIdx.x * 256 + threadIdx.x;
  int lane = threadIdx.x & 63;
  int c = (n < N) ? cnt[n] : 0;
  int incl = c;
#pragma unroll
  for (int off = 1; off < 64; off <<= 1) {
    int t = __shfl_up(incl, off, 64);
    if (lane >= off) incl += t;
  }
  int base = 0;
  if (lane == 63) base = atomicAdd(total, incl);
  base = __shfl(base, 63, 64);
  if (n < N) {
    int o = base + incl - c;
    offs[n] = o;
    cursor[n] = o;
  }
}

__global__ __launch_bounds__(256) void k_bin(const int* __restrict__ src,
                                             const int* __restrict__ dst,
                                             int* __restrict__ cursor,
                                             int2* __restrict__ csr, int E) {
  int e = blockIdx.x * 256 + threadIdx.x;
  if (e >= E) return;
  int d = dst[e];
  int pos = atomicAdd(cursor + d, 1);
  csr[pos] = make_int2(e, src[e]);
}

// ---------------- aggregate + combine: wave per node, lane = feature --------
__global__ __launch_bounds__(256) void k_agg(
    const float* __restrict__ node, const float* __restrict__ edge,
    const int2* __restrict__ csr, const int* __restrict__ offs,
    const int* __restrict__ cnt, const float* __restrict__ epsp,
    float* __restrict__ h, int N)
{
  int wid = (blockIdx.x * 256 + threadIdx.x) >> 6;
  int lane = threadIdx.x & 63;
  if (wid >= N) return;
  int start = offs[wid];
  int c = cnt[wid];
  float acc = 0.0f;
  for (int i = 0; i < c; ++i) {
    int2 p = csr[start + i];
    acc += edge[(size_t)p.x * D + lane] + node[(size_t)p.y * D + lane];
  }
  float inv = (c > 0) ? (1.0f / (float)c) : 0.0f;
  float hv = fmaf(1.0f + epsp[0], node[(size_t)wid * D + lane], acc * inv);
  h[(size_t)wid * D + lane] = hv;
}

// ---------------- GEMM1 + BN1 stats ---------------------
__global__ __launch_bounds__(256) void k_gemm1(
    const float* __restrict__ h, const float* __restrict__ W1,
    const float* __restrict__ b1, float* __restrict__ h1,
    float* __restrict__ sum1, float* __restrict__ sq1, int N)
{
  int row = blockIdx.x * 256 + threadIdx.x;
  bool active = row < N;
  float x[D];
  if (active) {
#pragma unroll
    for (int j = 0; j < D; j += 4) {
      float4 v = *(const float4*)(h + (size_t)row * D + j);
      x[j + 0] = v.x; x[j + 1] = v.y; x[j + 2] = v.z; x[j + 3] = v.w;
    }
  } else {
#pragma unroll
    for (int j = 0; j < D; ++j) x[j] = 0.0f;
  }

  for (int k = 0; k < H; k += 4) {
    float a0 = b1[k + 0], a1 = b1[k + 1], a2 = b1[k + 2], a3 = b1[k + 3];
#pragma unroll
    for (int j = 0; j < D; ++j) {
      float4 wv = *(const float4*)(W1 + (size_t)j * H + k);  // uniform -> s_load
      a0 = fmaf(x[j], wv.x, a0);
      a1 = fmaf(x[j], wv.y, a1);
      a2 = fmaf(x[j], wv.z, a2);
      a3 = fmaf(x[j], wv.w, a3);
    }
    float v0 = active ? a0 : 0.0f;
    float v1 = active ? a1 : 0.0f;
    float v2 = active ? a2 : 0.0f;
    float v3 = active ? a3 : 0.0f;
    float s0 = wave_sum(v0), q0 = wave_sum(v0 * v0);
    float s1 = wave_sum(v1), q1 = wave_sum(v1 * v1);
    float s2 = wave_sum(v2), q2 = wave_sum(v2 * v2);
    float s3 = wave_sum(v3), q3 = wave_sum(v3 * v3);
    if ((threadIdx.x & 63) == 0) {
      atomicAdd(sum1 + k + 0, s0); atomicAdd(sq1 + k + 0, q0);
      atomicAdd(sum1 + k + 1, s1); atomicAdd(sq1 + k + 1, q1);
      atomicAdd(sum1 + k + 2, s2); atomicAdd(sq1 + k + 2, q2);
      atomicAdd(sum1 + k + 3, s3); atomicAdd(sq1 + k + 3, q3);
    }
    if (active) *(float4*)(h1 + (size_t)row * H + k) = make_float4(a0, a1, a2, a3);
  }
}

// ---------------- BN finalize -----------------------
__global__ void k_finalize(const float* __restrict__ sum, const float* __restrict__ sq,
                           const float* __restrict__ gamma, const float* __restrict__ beta,
                           float* __restrict__ scale, float* __restrict__ shift,
                           int C, float invN)
{
  int k = threadIdx.x;
  if (k < C) {
    float m = sum[k] * invN;
    float var = fmaf(-m, m, sq[k] * invN);
    float sc = gamma[k] * rsqrtf(var + 1e-5f);
    scale[k] = sc;
    shift[k] = fmaf(-m, sc, beta[k]);
  }
}

// ---------------- BN1+ReLU + GEMM2 + BN2 stats --------------------
__global__ __launch_bounds__(256) void k_gemm2(
    const float* __restrict__ h1, const float* __restrict__ scale1,
    const float* __restrict__ shift1, const float* __restrict__ W2,
    const float* __restrict__ b2, float* __restrict__ out,
    float* __restrict__ sum2, float* __restrict__ sq2, int N)
{
  int row = blockIdx.x * 256 + threadIdx.x;
  bool active = row < N;
  float acc[D];
#pragma unroll
  for (int k = 0; k < D; ++k) acc[k] = 0.0f;

  if (active) {
    for (int j = 0; j < H; j += 4) {
      float4 hv = *(const float4*)(h1 + (size_t)row * H + j);
      float x0 = fmaxf(fmaf(hv.x, scale1[j + 0], shift1[j + 0]), 0.0f);
      float x1 = fmaxf(fmaf(hv.y, scale1[j + 1], shift1[j + 1]), 0.0f);
      float x2 = fmaxf(fmaf(hv.z, scale1[j + 2], shift1[j + 2]), 0.0f);
      float x3 = fmaxf(fmaf(hv.w, scale1[j + 3], shift1[j + 3]), 0.0f);
      const float* w0 = W2 + (size_t)(j + 0) * D;
      const float* w1 = W2 + (size_t)(j + 1) * D;
      const float* w2 = W2 + (size_t)(j + 2) * D;
      const float* w3 = W2 + (size_t)(j + 3) * D;
#pragma unroll
      for (int k = 0; k < D; ++k) {
        float a = acc[k];
        a = fmaf(x0, w0[k], a);
        a = fmaf(x1, w1[k], a);
        a = fmaf(x2, w2[k], a);
        a = fmaf(x3, w3[k], a);
        acc[k] = a;
      }
    }
  }

  for (int k = 0; k < D; k += 4) {
    float a0 = acc[k + 0] + b2[k + 0];
    float a1 = acc[k + 1] + b2[k + 1];
    float a2 = acc[k + 2] + b2[k + 2];
    float a3 = acc[k + 3] + b2[k + 3];
    float v0 = active ? a0 : 0.0f;
    float v1 = active ? a1 : 0.0f;
    float v2 = active ? a2 : 0.0f;
    float v3 = active ? a3 : 0.0f;
    float s0 = wave_sum(v0), q0 = wave_sum(v0 * v0);
    float s1 = wave_sum(v1), q1 = wave_sum(v1 * v1);
    float s2 = wave_sum(v2), q2 = wave_sum(v2 * v2);
    float s3 = wave_sum(v3), q3 = wave_sum(v3 * v3);
    if ((threadIdx.x & 63) == 0) {
      atomicAdd(sum2 + k + 0, s0); atomicAdd(sq2 + k + 0, q0);
      atomicAdd(sum2 + k + 1, s1); atomicAdd(sq2 + k + 1, q1);
      atomicAdd(sum2 + k + 2, s2); atomicAdd(sq2 + k + 2, q2);
      atomicAdd(sum2 + k + 3, s3); atomicAdd(sq2 + k + 3, q3);
    }
    if (active) *(float4*)(out + (size_t)row * D + k) = make_float4(a0, a1, a2, a3);
  }
}

// ---------------- final BN2 + ReLU (in-place on d_out) ------------
__global__ __launch_bounds__(256) void k_bnrelu(
    float* __restrict__ out, const float* __restrict__ scale2,
    const float* __restrict__ shift2, size_t n4)
{
  size_t idx = (size_t)blockIdx.x * 256 + threadIdx.x;
  if (idx >= n4) return;
  int k = (int)((idx * 4) & (D - 1));
  float4 v = *(float4*)(out + idx * 4);
  v.x = fmaxf(fmaf(v.x, scale2[k + 0], shift2[k + 0]), 0.0f);
  v.y = fmaxf(fmaf(v.y, scale2[k + 1], shift2[k + 1]), 0.0f);
  v.z = fmaxf(fmaf(v.z, scale2[k + 2], shift2[k + 2]), 0.0f);
  v.w = fmaxf(fmaf(v.w, scale2[k + 3], shift2[k + 3]), 0.0f);
  *(float4*)(out + idx * 4) = v;
}

extern "C" void kernel_launch(void* const* d_in, const int* in_sizes, int n_in,
                              void* d_out, int out_size, void* d_ws, size_t ws_size,
                              hipStream_t stream)
{
  const float* node   = (const float*)d_in[0];
  const float* edge   = (const float*)d_in[1];
  const int*   src    = (const int*)d_in[2];
  const int*   dst    = (const int*)d_in[3];
  const float* eps    = (const float*)d_in[4];
  const float* W1     = (const float*)d_in[5];
  const float* b1     = (const float*)d_in[6];
  const float* gamma1 = (const float*)d_in[7];
  const float* beta1  = (const float*)d_in[8];
  const float* W2     = (const float*)d_in[9];
  const float* b2     = (const float*)d_in[10];
  const float* gamma2 = (const float*)d_in[11];
  const float* beta2  = (const float*)d_in[12];
  float* out = (float*)d_out;

  const int N = in_sizes[0] / D;
  const int E = in_sizes[2];

  // workspace layout in 4-byte words:
  //   0: sum1(H) 128: sq1(H) 256: sum2(D) 320: sq2(D)
  //   384: scale1(H) 512: shift1(H) 640: scale2(D) 704: shift2(D)
  //   768: total(1) [pad to 832]
  //   832: cnt(N)  832+N: offs(N)  832+2N: cursor(N)
  //   832+3N: h(N*D)
  //   832+3N+N*D: csr(2E) aliased with h1(N*H)  [lifetimes disjoint]
  char* base = (char*)d_ws;
  float* sum1   = (float*)base;
  float* sq1    = sum1 + H;
  float* sum2   = sq1 + H;
  float* sq2    = sum2 + D;
  float* scale1 = sq2 + D;
  float* shift1 = scale1 + H;
  float* scale2 = shift1 + H;
  float* shift2 = scale2 + D;
  int*   total  = (int*)(shift2 + D);          // word 768
  int*   cnt    = (int*)base + 832;
  int*   offs   = cnt + N;
  int*   cursor = offs + N;
  float* h      = (float*)(cursor + N);
  int2*  csr    = (int2*)(h + (size_t)N * D);
  float* h1     = (float*)csr;

  // zero: stats (0..384), total (768), cnt — one contiguous memset of the
  // first 832+N words covers all of them (scale/shift are write-before-read)
  hipMemsetAsync(d_ws, 0, (size_t)(832 + N) * sizeof(int), stream);

  int ebn = (E + 255) / 256;
  int nbn = (N + 255) / 256;
  k_hist<<<ebn, 256, 0, stream>>>(dst, cnt, E);
  k_alloc<<<nbn, 256, 0, stream>>>(cnt, offs, cursor, total, N);
  k_bin<<<ebn, 256, 0, stream>>>(src, dst, cursor, csr, E);
  k_agg<<<(N * 64 + 255) / 256, 256, 0, stream>>>(node, edge, csr, offs, cnt, eps, h, N);

  k_gemm1<<<nbn, 256, 0, stream>>>(h, W1, b1, h1, sum1, sq1, N);
  k_finalize<<<1, H, 0, stream>>>(sum1, sq1, gamma1, beta1, scale1, shift1, H, 1.0f / (float)N);
  k_gemm2<<<nbn, 256, 0, stream>>>(h1, scale1, shift1, W2, b2, out, sum2, sq2, N);
  k_finalize<<<1, D, 0, stream>>>(sum2, sq2, gamma2, beta2, scale2, shift2, D, 1.0f / (float)N);

  size_t n4 = (size_t)N * D / 4;
  k_bnrelu<<<(int)((n4 + 255) / 256), 256, 0, stream>>>(out, scale2, shift2, n4);
}